// Round 3
// baseline (11731.079 us; speedup 1.0000x reference)
//
#include <hip/hip_runtime.h>

typedef _Float16 f16;
typedef _Float16 f16x8 __attribute__((ext_vector_type(8)));
typedef _Float16 h2    __attribute__((ext_vector_type(2)));
typedef float    f32x4 __attribute__((ext_vector_type(4)));
typedef unsigned int uint;

#define ALPHA 0.2f
#define NSTD  0.05f
#define BB 128
#define TT 1024
#define II 64
#define HH 512
#define OO 10

#define MB   16            // batch elements per block (MFMA M, fully used)
#define NB   (BB / MB)     // 8 blocks
#define NAGA 13            // wrec K-tiles pinned in AGPRs (tiles 0..12)
#define NLD  3             // wrec K-tiles in LDS (tiles 13..15)
#define NTR  18            // r tiles: 16 wrec-K + 2 wi-K

// Explicit AGPR pinning (round-0-proven safe pattern). All MFMAs stay
// builtins so the compiler inserts every MFMA hazard nop; the only asm
// producer (accvgpr_read -> MFMA SrcB) is guarded by a tied s_nop 1.
#define AGPR_WRITE(dst, src) asm volatile("v_accvgpr_write_b32 %0, %1" : "=a"(dst) : "v"(src))
#define AGPR_READ(dst, src)  asm volatile("v_accvgpr_read_b32 %0, %1" : "=v"(dst) : "a"(src))

__device__ __forceinline__ f32x4 mfma16(f16x8 a, f16x8 b, f32x4 c) {
    return __builtin_amdgcn_mfma_f32_16x16x32_f16(a, b, c, 0, 0, 0);
}

// r_lds packed layout: f16x8 frag index = kt*64 + lg*16 + (lr ^ s(kt,lg)),
// s(kt,lg) = 4*(kt&1) + lg. Lane l = lg*16+lr reads frag kt*64 + swz(l):
// exactly 64 distinct 16B slots per tile -> linear, conflict-free reads.
// The XOR spreads the scalar publish writes to ~2-way (free).
__global__ __launch_bounds__(512, 2) void rnn_kernel(
    const float* __restrict__ input, const float* __restrict__ noise,
    const float* __restrict__ wi, const float* __restrict__ si,
    const float* __restrict__ wrec, const float* __restrict__ wo,
    const float* __restrict__ so, const float* __restrict__ h0,
    float* __restrict__ out)
{
    __shared__ __align__(16) f16 rpack[2][NTR * 512];  // 36 KB (double buffer)
    __shared__ f16x8 wrecL[NLD][32][64];               // 96 KB (wrec tiles 13..15)
    __shared__ f32x4 opart[2][8][64];                  // 16 KB (out partials, dbuf)

    const int tid = threadIdx.x, l = tid & 63, g = tid >> 6;
    const int lr = l & 15, lg = l >> 4;
    const int b0 = blockIdx.x * MB;

    // ---- AGPR-pinned weight fragments: wrec tiles 0..12 + wi tiles (240 regs) ----
    uint wag[NAGA + 2][4][4];
#pragma unroll
    for (int kt = 0; kt < NAGA; ++kt)
#pragma unroll
        for (int nt = 0; nt < 4; ++nt) {
            const float* wp = wrec + (size_t)((4*g + nt)*16 + lr)*HH + kt*32 + lg*8;
            float4 a0 = *(const float4*)wp;
            float4 a1 = *(const float4*)(wp + 4);
            f16x8 v;
            v[0]=(f16)a0.x; v[1]=(f16)a0.y; v[2]=(f16)a0.z; v[3]=(f16)a0.w;
            v[4]=(f16)a1.x; v[5]=(f16)a1.y; v[6]=(f16)a1.z; v[7]=(f16)a1.w;
            uint4 u = __builtin_bit_cast(uint4, v);
            AGPR_WRITE(wag[kt][nt][0], u.x);
            AGPR_WRITE(wag[kt][nt][1], u.y);
            AGPR_WRITE(wag[kt][nt][2], u.z);
            AGPR_WRITE(wag[kt][nt][3], u.w);
        }
#pragma unroll
    for (int k2 = 0; k2 < 2; ++k2)
#pragma unroll
        for (int nt = 0; nt < 4; ++nt) {
            const int hcol = (4*g + nt)*16 + lr;
            f16x8 v;
#pragma unroll
            for (int jj = 0; jj < 8; ++jj) {
                const int i = k2*32 + lg*8 + jj;
                v[jj] = (f16)(wi[(size_t)i*HH + hcol] * si[i]);
            }
            uint4 u = __builtin_bit_cast(uint4, v);
            AGPR_WRITE(wag[NAGA + k2][nt][0], u.x);
            AGPR_WRITE(wag[NAGA + k2][nt][1], u.y);
            AGPR_WRITE(wag[NAGA + k2][nt][2], u.z);
            AGPR_WRITE(wag[NAGA + k2][nt][3], u.w);
        }
    // ---- LDS wrec tiles 13..15 (B-frags, lane-linear) ----
#pragma unroll
    for (int ktL = 0; ktL < NLD; ++ktL)
#pragma unroll
        for (int c = 0; c < 4; ++c) {
            const int nt = c*8 + g;
            const float* wp = wrec + (size_t)(nt*16 + lr)*HH + (NAGA + ktL)*32 + lg*8;
            float4 a0 = *(const float4*)wp;
            float4 a1 = *(const float4*)(wp + 4);
            f16x8 v;
            v[0]=(f16)a0.x; v[1]=(f16)a0.y; v[2]=(f16)a0.z; v[3]=(f16)a0.w;
            v[4]=(f16)a1.x; v[5]=(f16)a1.y; v[6]=(f16)a1.z; v[7]=(f16)a1.w;
            wrecL[ktL][nt][l] = v;
        }
    // ---- output weights (VGPR; builtin out-MFMA) ----
    f16x8 bwo[2];
    {
        const float s = (lr < OO) ? so[lr] * (1.0f/ALPHA) : 0.0f;
#pragma unroll
        for (int k2 = 0; k2 < 2; ++k2) {
            f16x8 v;
#pragma unroll
            for (int jj = 0; jj < 8; ++jj) {
                const int k = (2*g + k2)*32 + lg*8 + jj;
                v[jj] = (f16)((lr < OO) ? wo[(size_t)k*OO + lr] * s : 0.0f);
            }
            bwo[k2] = v;
        }
    }

    // ---- swizzled read offsets (compile-time parity per tile) ----
    const int ide = lg*16 + (lr ^ lg);        // even tiles
    const int ido = lg*16 + (lr ^ (4 + lg));  // odd tiles

    // ---- publish bases: value (row=4lg+rr, col=64g+16nt+lr) ----
    int wbase[4], wxor[4];
#pragma unroll
    for (int nt = 0; nt < 4; ++nt) {
        const int col = 64*g + 16*nt + lr;
        const int ktw = col >> 5, lgw = (col >> 3) & 3, j = col & 7;
        const int s = 4*(ktw & 1) + lgw;
        wbase[nt] = ktw*512 + lgw*128 + ((4*lg) ^ (s & 4))*8 + j;
        wxor[nt]  = (s & 3)*8;
    }
    // x publish: thread covers (bb, ii..ii+1)
    const int bb = tid >> 5, ii = (tid & 31)*2;
    const int xkt = 16 + (ii >> 5), xlg = (ii >> 3) & 3;
    const int xsw = 4*(xkt & 1) + xlg;
    const int xbi = xkt*512 + xlg*128 + (bb ^ xsw)*8 + (ii & 7);

    // ---- state: hs[nt][rr] = h[batch 4lg+rr][col 64g+16nt+lr] ----
    f32x4 hs[4];
#pragma unroll
    for (int nt = 0; nt < 4; ++nt) {
        const float v = h0[(4*g + nt)*16 + lr];
        hs[nt] = f32x4{v, v, v, v};
    }

    // noise: 4 row pointers, 16 scalars prefetched one step ahead
    const float* nptr[4];
#pragma unroll
    for (int rr = 0; rr < 4; ++rr)
        nptr[rr] = noise + (size_t)(b0 + 4*lg + rr)*TT*HH + 64*g + lr;
    float nz[4][4];
#pragma unroll
    for (int nt = 0; nt < 4; ++nt)
#pragma unroll
        for (int rr = 0; rr < 4; ++rr) nz[nt][rr] = nptr[rr][nt*16];

    // x staging, prefetched one step ahead
    const float* xbase = input + (size_t)(b0 + bb)*TT*II + ii;
    float2 xv = *(const float2*)xbase;                 // x_0

    // ---- publish r_0 + alpha*x_0 into buffer 0 ----
    {
        f16* rpn = rpack[0];
#pragma unroll
        for (int nt = 0; nt < 4; ++nt)
#pragma unroll
            for (int rr = 0; rr < 4; ++rr)
                rpn[wbase[nt] + ((rr*8) ^ wxor[nt])] =
                    (f16)(ALPHA * fmaxf(hs[nt][rr], 0.0f));
        h2 xp; xp[0] = (f16)(ALPHA*xv.x); xp[1] = (f16)(ALPHA*xv.y);
        *(h2*)(rpn + xbi) = xp;
    }
    const float* xq = xbase + II;
    xv = *(const float2*)xq;  xq += II;                // x_1

    const float* outp = nullptr; (void)outp;
    float* outb = out + (size_t)b0 * TT * OO;

    __syncthreads();

    int cur = 0;
#pragma unroll 1
    for (int t = 0; t < TT; ++t) {
        const f16x8* rvb = (const f16x8*)rpack[cur];

        // h pre-accumulate: (1-a)h + sigma*n_t  (MFMA C operand)
#pragma unroll
        for (int nt = 0; nt < 4; ++nt) {
            f32x4 a = hs[nt];
#pragma unroll
            for (int rr = 0; rr < 4; ++rr)
                a[rr] = (1.0f - ALPHA)*a[rr] + NSTD*nz[nt][rr];
            hs[nt] = a;
        }
        // prefetch n_{t+1}
        if (t + 1 < TT) {
#pragma unroll
            for (int rr = 0; rr < 4; ++rr) nptr[rr] += HH;
#pragma unroll
            for (int nt = 0; nt < 4; ++nt)
#pragma unroll
                for (int rr = 0; rr < 4; ++rr) nz[nt][rr] = nptr[rr][nt*16];
        }

        // out-MFMA: out[t-1] = relu(h_t) @ wo_full
        {
            const f16x8 aA = rvb[(2*g)*64     + ide];
            const f16x8 aB = rvb[(2*g + 1)*64 + ido];
            f32x4 oacc = mfma16(aA, bwo[0], f32x4{0.f, 0.f, 0.f, 0.f});
            oacc = mfma16(aB, bwo[1], oacc);
            opart[cur][g][l] = oacc;
        }

        // main chain: AGPR wrec tiles 0..12
#pragma unroll
        for (int kt = 0; kt < NAGA; ++kt) {
            const f16x8 a = rvb[kt*64 + ((kt & 1) ? ido : ide)];
#pragma unroll
            for (int nt = 0; nt < 4; ++nt) {
                uint w0, w1, w2, w3;
                AGPR_READ(w0, wag[kt][nt][0]);
                AGPR_READ(w1, wag[kt][nt][1]);
                AGPR_READ(w2, wag[kt][nt][2]);
                AGPR_READ(w3, wag[kt][nt][3]);
                asm volatile("s_nop 1" : "+v"(w0), "+v"(w1), "+v"(w2), "+v"(w3));
                uint4 u = make_uint4(w0, w1, w2, w3);
                hs[nt] = mfma16(a, __builtin_bit_cast(f16x8, u), hs[nt]);
            }
        }
        // LDS wrec tiles 13..15
#pragma unroll
        for (int ktL = 0; ktL < NLD; ++ktL) {
            const int kt = NAGA + ktL;
            const f16x8 a = rvb[kt*64 + ((kt & 1) ? ido : ide)];
#pragma unroll
            for (int nt = 0; nt < 4; ++nt)
                hs[nt] = mfma16(a, wrecL[ktL][4*g + nt][l], hs[nt]);
        }
        // wi tiles 16,17 (AGPR)
#pragma unroll
        for (int k2 = 0; k2 < 2; ++k2) {
            const int kt = 16 + k2;
            const f16x8 a = rvb[kt*64 + ((kt & 1) ? ido : ide)];
#pragma unroll
            for (int nt = 0; nt < 4; ++nt) {
                uint w0, w1, w2, w3;
                AGPR_READ(w0, wag[NAGA + k2][nt][0]);
                AGPR_READ(w1, wag[NAGA + k2][nt][1]);
                AGPR_READ(w2, wag[NAGA + k2][nt][2]);
                AGPR_READ(w3, wag[NAGA + k2][nt][3]);
                asm volatile("s_nop 1" : "+v"(w0), "+v"(w1), "+v"(w2), "+v"(w3));
                uint4 u = make_uint4(w0, w1, w2, w3);
                hs[nt] = mfma16(a, __builtin_bit_cast(f16x8, u), hs[nt]);
            }
        }

        // publish r_{t+1} (+ alpha*x_{t+1}) into the other buffer
        const int nxt = cur ^ 1;
        {
            f16* rpn = rpack[nxt];
#pragma unroll
            for (int nt = 0; nt < 4; ++nt)
#pragma unroll
                for (int rr = 0; rr < 4; ++rr)
                    rpn[wbase[nt] + ((rr*8) ^ wxor[nt])] =
                        (f16)(ALPHA * fmaxf(hs[nt][rr], 0.0f));
            if (t + 1 < TT) {
                h2 xp; xp[0] = (f16)(ALPHA*xv.x); xp[1] = (f16)(ALPHA*xv.y);
                *(h2*)(rpn + xbi) = xp;
                if (t + 2 < TT) { xv = *(const float2*)xq; xq += II; }
            }
        }

        __syncthreads();   // rpack[nxt] + opart[cur] visible

        if (g == 7 && t > 0) {
            f32x4 s = opart[cur][0][l];
#pragma unroll
            for (int w = 1; w < 8; ++w) s += opart[cur][w][l];
            if (lr < OO) {
#pragma unroll
                for (int rr = 0; rr < 4; ++rr)
                    outb[((size_t)(4*lg + rr)*TT + (t - 1))*OO + lr] = s[rr];
            }
        }
        cur = nxt;
    }

    // drain: out[T-1] from rpack[cur] = alpha*relu(h_T)
    {
        const f16x8* rvb = (const f16x8*)rpack[cur];
        const f16x8 aA = rvb[(2*g)*64     + ide];
        const f16x8 aB = rvb[(2*g + 1)*64 + ido];
        f32x4 oacc = mfma16(aA, bwo[0], f32x4{0.f, 0.f, 0.f, 0.f});
        oacc = mfma16(aB, bwo[1], oacc);
        opart[cur][g][l] = oacc;
    }
    __syncthreads();
    if (g == 7) {
        f32x4 s = opart[cur][0][l];
#pragma unroll
        for (int w = 1; w < 8; ++w) s += opart[cur][w][l];
        if (lr < OO) {
#pragma unroll
            for (int rr = 0; rr < 4; ++rr)
                outb[((size_t)(4*lg + rr)*TT + (TT - 1))*OO + lr] = s[rr];
        }
    }
}

extern "C" void kernel_launch(void* const* d_in, const int* in_sizes, int n_in,
                              void* d_out, int out_size, void* d_ws, size_t ws_size,
                              hipStream_t stream) {
    const float* input = (const float*)d_in[0];
    const float* noise = (const float*)d_in[1];
    const float* wi    = (const float*)d_in[2];
    const float* si    = (const float*)d_in[3];
    const float* wrec  = (const float*)d_in[4];
    const float* wo    = (const float*)d_in[5];
    const float* so    = (const float*)d_in[6];
    const float* h0    = (const float*)d_in[7];
    float* out = (float*)d_out;
    (void)d_ws; (void)ws_size; (void)in_sizes; (void)n_in; (void)out_size;

    rnn_kernel<<<dim3(NB), dim3(512), 0, stream>>>(
        input, noise, wi, si, wrec, wo, so, h0, out);
}

// Round 5
// 9861.794 us; speedup vs baseline: 1.1895x; 1.1895x over previous
//
#include <hip/hip_runtime.h>

typedef _Float16 f16;
typedef _Float16 f16x8 __attribute__((ext_vector_type(8)));
typedef float    f32x4 __attribute__((ext_vector_type(4)));

#define ALPHA 0.2f
#define NSTD  0.05f
#define BB 128
#define TT 1024
#define II 64
#define HH 512
#define OO 10

#define MB   2             // real batch rows per block (M padded to 16)
#define NBLK (BB / MB)     // 64 blocks
#define NT   2             // N-tiles per wave (32 cols); 16 waves cover N=512
#define NTR  18            // r tiles: 16 wrec-K + 2 wi-K

// All MFMAs are builtins (compiler handles every hazard). B-fragments are
// 18*NT*4 = 144 arch VGPRs per wave -> fits the 256 cap, no AGPR moves,
// no spill. LDS carries only the A-fragments (r) and out partials.
__device__ __forceinline__ f32x4 mfma16(f16x8 a, f16x8 b, f32x4 c) {
    return __builtin_amdgcn_mfma_f32_16x16x32_f16(a, b, c, 0, 0, 0);
}

// rpack layout (round-3-verified, 0 bank conflicts): f16x8 frag index =
// kt*64 + lg*16 + (lr ^ s(kt,lg)), s = 4*(kt&1)+lg; element jj = k&7.
// Every rpack slot has EXACTLY ONE writer thread (round-4 race removed:
// fake-row x slots are re-published as 0 every step, no persistent zeros).
__global__ __launch_bounds__(1024, 4) void rnn_kernel(
    const float* __restrict__ input, const float* __restrict__ noise,
    const float* __restrict__ wi, const float* __restrict__ si,
    const float* __restrict__ wrec, const float* __restrict__ wo,
    const float* __restrict__ so, const float* __restrict__ h0,
    float* __restrict__ out)
{
    __shared__ __align__(16) f16 rpack[2][NTR * 512];  // 36 KB (double buffer)
    __shared__ f32x4 opart[2][16][64];                 // 32 KB (out partials, dbuf)

    const int tid = threadIdx.x, l = tid & 63, g = tid >> 6;   // g = 0..15
    const int lr = l & 15, lg = l >> 4;
    const int b0 = blockIdx.x * MB;

    // ---- B-fragments, all arch-VGPR-resident (144 regs) ----
    f16x8 bw[NTR][NT];
#pragma unroll
    for (int kt = 0; kt < 16; ++kt)
#pragma unroll
        for (int nt = 0; nt < NT; ++nt) {
            const int col = 32*g + 16*nt + lr;
            const float* wp = wrec + (size_t)col*HH + kt*32 + lg*8;
            float4 a0 = *(const float4*)wp;
            float4 a1 = *(const float4*)(wp + 4);
            f16x8 v;
            v[0]=(f16)a0.x; v[1]=(f16)a0.y; v[2]=(f16)a0.z; v[3]=(f16)a0.w;
            v[4]=(f16)a1.x; v[5]=(f16)a1.y; v[6]=(f16)a1.z; v[7]=(f16)a1.w;
            bw[kt][nt] = v;
        }
#pragma unroll
    for (int k2 = 0; k2 < 2; ++k2)
#pragma unroll
        for (int nt = 0; nt < NT; ++nt) {
            const int col = 32*g + 16*nt + lr;
            f16x8 v;
#pragma unroll
            for (int jj = 0; jj < 8; ++jj) {
                const int e = k2*32 + lg*8 + jj;      // 0..63
                v[jj] = (f16)(wi[(size_t)e*HH + col] * si[e]);
            }
            bw[16 + k2][nt] = v;
        }
    // out weights: wave g covers K-tile g (k = 32g + lg*8 + jj), cols = outputs
    f16x8 bwo;
    {
        const float s = (lr < OO) ? so[lr] * (1.0f/ALPHA) : 0.0f;
#pragma unroll
        for (int jj = 0; jj < 8; ++jj) {
            const int k = 32*g + lg*8 + jj;
            bwo[jj] = (f16)((lr < OO) ? wo[(size_t)k*OO + lr] * s : 0.0f);
        }
    }

    // ---- swizzled A-read offsets ----
    const int ide = lg*16 + (lr ^ lg);        // even tiles
    const int ido = lg*16 + (lr ^ (4 + lg));  // odd tiles

    // ---- publish bases for h (row = 4lg+rr, col = 32g+16nt+lr) ----
    int wbase[NT], wxor[NT];
#pragma unroll
    for (int nt = 0; nt < NT; ++nt) {
        const int col = 32*g + 16*nt + lr;
        const int ktw = col >> 5, lgw = (col >> 3) & 3, j = col & 7;
        const int s = 4*(ktw & 1) + lgw;
        wbase[nt] = ktw*512 + lgw*128 + ((4*lg) ^ (s & 4))*8 + j;
        wxor[nt]  = (s & 3)*8;
    }
    // x publish: EVERY thread owns one slot (row = tid>>6 in 0..15, ii = tid&63);
    // fake rows (xrow >= MB) publish 0 every step.
    const int xrow = tid >> 6, xii = tid & 63;
    const bool ldx = (xrow < MB);
    const int xkt = 16 + (xii >> 5), xlg = (xii >> 3) & 3;
    const int xsw = 4*(xkt & 1) + xlg;
    const int xbi = xkt*512 + xlg*128 + (xrow ^ xsw)*8 + (xii & 7);

    // ---- state: hs[nt][rr] = h[row 4lg+rr][col 32g+16nt+lr] (C/D layout) ----
    f32x4 hs[NT];
#pragma unroll
    for (int nt = 0; nt < NT; ++nt) {
        const float v = h0[32*g + 16*nt + lr];
        hs[nt] = f32x4{v, v, v, v};
    }

    // ---- noise: only real rows (lg==0, rr<MB); depth-2 register ring ----
    const bool ldn = (lg == 0);
    const float* np[NT][MB];
#pragma unroll
    for (int nt = 0; nt < NT; ++nt)
#pragma unroll
        for (int rr = 0; rr < MB; ++rr)
            np[nt][rr] = noise + (size_t)(b0 + rr)*TT*HH + 32*g + 16*nt + lr;
    float nzA[NT][MB] = {}, nzB[NT][MB] = {};
    if (ldn) {
#pragma unroll
        for (int nt = 0; nt < NT; ++nt)
#pragma unroll
            for (int rr = 0; rr < MB; ++rr) {
                nzA[nt][rr] = np[nt][rr][0];
                nzB[nt][rr] = np[nt][rr][HH];
            }
    }

    // ---- x staging, one step ahead ----
    const float* xp = input + (size_t)(b0 + xrow)*TT*II + xii;
    float xv = ldx ? xp[0] : 0.0f;                     // x_0 (0 for fake rows)

    // ---- publish r_0 + alpha*x_0 into buffer 0 (single writer per slot) ----
#pragma unroll
    for (int nt = 0; nt < NT; ++nt)
#pragma unroll
        for (int rr = 0; rr < 4; ++rr)
            rpack[0][wbase[nt] + ((rr*8) ^ wxor[nt])] =
                (f16)(ALPHA * fmaxf(hs[nt][rr], 0.0f));
    rpack[0][xbi] = (f16)(ALPHA * xv);
    if (ldx) xv = xp[II];                              // x_1

    float* outb = out + (size_t)b0 * TT * OO;

    __syncthreads();

    int cur = 0;
#pragma unroll 1
    for (int t = 0; t < TT; ++t) {
        const f16x8* rvb = (const f16x8*)rpack[cur];

        // C pre-accumulate: (1-a)h + sigma*n_t ; prefetch n_{t+2}
        if (t & 1) {
#pragma unroll
            for (int nt = 0; nt < NT; ++nt)
#pragma unroll
                for (int rr = 0; rr < 4; ++rr) {
                    float nv = (rr < MB) ? nzB[nt][rr] : 0.0f;
                    hs[nt][rr] = (1.0f - ALPHA)*hs[nt][rr] + NSTD*nv;
                }
            if (ldn && t + 2 < TT) {
#pragma unroll
                for (int nt = 0; nt < NT; ++nt)
#pragma unroll
                    for (int rr = 0; rr < MB; ++rr)
                        nzB[nt][rr] = np[nt][rr][(size_t)(t + 2)*HH];
            }
        } else {
#pragma unroll
            for (int nt = 0; nt < NT; ++nt)
#pragma unroll
                for (int rr = 0; rr < 4; ++rr) {
                    float nv = (rr < MB) ? nzA[nt][rr] : 0.0f;
                    hs[nt][rr] = (1.0f - ALPHA)*hs[nt][rr] + NSTD*nv;
                }
            if (ldn && t + 2 < TT) {
#pragma unroll
                for (int nt = 0; nt < NT; ++nt)
#pragma unroll
                    for (int rr = 0; rr < MB; ++rr)
                        nzA[nt][rr] = np[nt][rr][(size_t)(t + 2)*HH];
            }
        }

        // out-MFMA: wave g contributes K-tile g of out[t-1] = relu(h_t) @ wo'
        {
            const f16x8 a = rvb[g*64 + ((g & 1) ? ido : ide)];
            opart[cur][g][l] = mfma16(a, bwo, f32x4{0.f, 0.f, 0.f, 0.f});
        }

        // main chain: h_{t+1} += r_t @ W  (18 K-tiles, nt=2 ILP)
#pragma unroll
        for (int kt = 0; kt < NTR; ++kt) {
            const f16x8 a = rvb[kt*64 + ((kt & 1) ? ido : ide)];
#pragma unroll
            for (int nt = 0; nt < NT; ++nt)
                hs[nt] = mfma16(a, bw[kt][nt], hs[nt]);
        }

        // publish r_{t+1} (+ alpha*x_{t+1}; fake rows publish 0) into other buffer
        const int nxt = cur ^ 1;
#pragma unroll
        for (int nt = 0; nt < NT; ++nt)
#pragma unroll
            for (int rr = 0; rr < 4; ++rr)
                rpack[nxt][wbase[nt] + ((rr*8) ^ wxor[nt])] =
                    (f16)(ALPHA * fmaxf(hs[nt][rr], 0.0f));
        rpack[nxt][xbi] = (f16)(ALPHA * xv);
        if (ldx && t + 2 < TT) xv = xp[(size_t)(t + 2)*II];

        __syncthreads();   // rpack[nxt] + opart[cur] visible

        if (g == 15 && t > 0) {
            f32x4 s = opart[cur][0][l];
#pragma unroll
            for (int w = 1; w < 16; ++w) s += opart[cur][w][l];
            if (lg == 0 && lr < OO) {
#pragma unroll
                for (int rr = 0; rr < MB; ++rr)
                    outb[((size_t)rr*TT + (t - 1))*OO + lr] = s[rr];
            }
        }
        cur = nxt;
    }

    // drain: out[T-1] from rpack[cur] = alpha*relu(h_T)
    {
        const f16x8* rvb = (const f16x8*)rpack[cur];
        const f16x8 a = rvb[g*64 + ((g & 1) ? ido : ide)];
        opart[cur][g][l] = mfma16(a, bwo, f32x4{0.f, 0.f, 0.f, 0.f});
    }
    __syncthreads();
    if (g == 15) {
        f32x4 s = opart[cur][0][l];
#pragma unroll
        for (int w = 1; w < 16; ++w) s += opart[cur][w][l];
        if (lg == 0 && lr < OO) {
#pragma unroll
            for (int rr = 0; rr < MB; ++rr)
                outb[((size_t)rr*TT + (TT - 1))*OO + lr] = s[rr];
        }
    }
}

extern "C" void kernel_launch(void* const* d_in, const int* in_sizes, int n_in,
                              void* d_out, int out_size, void* d_ws, size_t ws_size,
                              hipStream_t stream) {
    const float* input = (const float*)d_in[0];
    const float* noise = (const float*)d_in[1];
    const float* wi    = (const float*)d_in[2];
    const float* si    = (const float*)d_in[3];
    const float* wrec  = (const float*)d_in[4];
    const float* wo    = (const float*)d_in[5];
    const float* so    = (const float*)d_in[6];
    const float* h0    = (const float*)d_in[7];
    float* out = (float*)d_out;
    (void)d_ws; (void)ws_size; (void)in_sizes; (void)n_in; (void)out_size;

    rnn_kernel<<<dim3(NBLK), dim3(1024), 0, stream>>>(
        input, noise, wi, si, wrec, wo, so, h0, out);
}

// Round 6
// 7072.367 us; speedup vs baseline: 1.6587x; 1.3944x over previous
//
#include <hip/hip_runtime.h>

typedef _Float16 f16;
typedef _Float16 f16x8 __attribute__((ext_vector_type(8)));
typedef float    f32x4 __attribute__((ext_vector_type(4)));
typedef unsigned int uint;

#define ALPHA 0.2f
#define NSTD  0.05f
#define BB 128
#define TT 1024
#define II 64
#define HH 512
#define OO 10

#define MB   2             // real batch rows per block (M padded to 16)
#define NBLK (BB / MB)     // 64 blocks
#define NW   8             // waves per block
#define NT   4             // N-tiles per wave (64 cols); 8 waves cover N=512
#define NTR  18            // r tiles: 16 wrec-K + 2 wi-K
#define NAGR 8             // wrec K-tiles 0..7 in arch VGPRs (128 regs)
#define NLDS 3             // wrec K-tiles 8..10 in LDS (96 KB, shared)
#define NSTR 7             // K-tiles 11..17 streamed from packed ws (L2)

#define WS_FRAGS (NSTR * 32 * 64)   // 14336 f16x8 frags
#define WS_NEED  (WS_FRAGS * 16)    // 224 KB

__device__ __forceinline__ f32x4 mfma16(f16x8 a, f16x8 b, f32x4 c) {
    return __builtin_amdgcn_mfma_f32_16x16x32_f16(a, b, c, 0, 0, 0);
}
__device__ __forceinline__ f16x8 pack8(float4 a0, float4 a1) {
    f16x8 v;
    v[0]=(f16)a0.x; v[1]=(f16)a0.y; v[2]=(f16)a0.z; v[3]=(f16)a0.w;
    v[4]=(f16)a1.x; v[5]=(f16)a1.y; v[6]=(f16)a1.z; v[7]=(f16)a1.w;
    return v;
}

// ---- one-time pack of streamed K-tiles 11..17 into d_ws ----
// frag fid = st*2048 + ntg*64 + l : B-frag (col=ntg*16+lr, k=(11+st)*32+lg*8+jj)
__global__ __launch_bounds__(512) void pack_kernel(
    const float* __restrict__ wrec, const float* __restrict__ wi,
    const float* __restrict__ si, uint4* __restrict__ ws)
{
    const int fid = blockIdx.x * 512 + threadIdx.x;      // < WS_FRAGS
    const int st = fid >> 11, rem = fid & 2047;
    const int ntg = rem >> 6, l = rem & 63;
    const int lr = l & 15, lg = l >> 4;
    const int col = ntg * 16 + lr;
    const int kt = 11 + st, k0 = kt * 32 + lg * 8;
    f16x8 v;
    if (kt < 16) {
#pragma unroll
        for (int jj = 0; jj < 8; ++jj) v[jj] = (f16)wrec[(size_t)col * HH + k0 + jj];
    } else {
#pragma unroll
        for (int jj = 0; jj < 8; ++jj) {
            const int e = k0 + jj - HH;                  // 0..63
            v[jj] = (f16)(wi[(size_t)e * HH + col] * si[e]);
        }
    }
    ws[fid] = __builtin_bit_cast(uint4, v);
}

// rpack layout (round-3/5-verified, 0 bank conflicts): f16x8 frag index =
// kt*64 + lg*16 + (lr ^ s(kt,lg)), s = 4*(kt&1)+lg; element jj = k&7.
// Single writer per slot; sync structure is round-5-verbatim (1 barrier + dbuf).
template<bool PACKED>
__global__ __attribute__((amdgpu_waves_per_eu(2, 2)))
__launch_bounds__(512) void rnn_kernel(
    const float* __restrict__ input, const float* __restrict__ noise,
    const float* __restrict__ wi, const float* __restrict__ si,
    const float* __restrict__ wrec, const float* __restrict__ wo,
    const float* __restrict__ so, const float* __restrict__ h0,
    const uint4* __restrict__ ws, float* __restrict__ out)
{
    __shared__ __align__(16) f16 rpack[2][NTR * 512];  // 36.8 KB (double buffer)
    __shared__ f16x8 wrecL[NLDS][32][64];              // 96 KB  (wrec tiles 8..10)
    __shared__ f32x4 opart[2][NW][64];                 // 16 KB  (out partials, dbuf)

    const int tid = threadIdx.x, l = tid & 63, g = tid >> 6;   // g = 0..7
    const int lr = l & 15, lg = l >> 4;
    const int b0 = blockIdx.x * MB;

    // ---- register B-fragments: wrec K-tiles 0..7 (128 arch VGPRs) ----
    f16x8 bw[NAGR][NT];
#pragma unroll
    for (int kt = 0; kt < NAGR; ++kt)
#pragma unroll
        for (int nt = 0; nt < NT; ++nt) {
            const int col = 64*g + 16*nt + lr;
            const float* wp = wrec + (size_t)col*HH + kt*32 + lg*8;
            bw[kt][nt] = pack8(*(const float4*)wp, *(const float4*)(wp + 4));
        }
    // ---- LDS B-fragments: wrec K-tiles 8..10, shared across waves ----
#pragma unroll
    for (int ktL = 0; ktL < NLDS; ++ktL)
#pragma unroll
        for (int c = 0; c < 4; ++c) {
            const int ntg = c*8 + g;                   // 8 waves cover 32 n-tiles
            const float* wp = wrec + (size_t)(ntg*16 + lr)*HH + (NAGR + ktL)*32 + lg*8;
            wrecL[ktL][ntg][l] = pack8(*(const float4*)wp, *(const float4*)(wp + 4));
        }
    // ---- out weights: wave g covers K-tiles 2g, 2g+1 ----
    f16x8 bwo[2];
    {
        const float s = (lr < OO) ? so[lr] * (1.0f/ALPHA) : 0.0f;
#pragma unroll
        for (int k2 = 0; k2 < 2; ++k2) {
            f16x8 v;
#pragma unroll
            for (int jj = 0; jj < 8; ++jj) {
                const int k = (2*g + k2)*32 + lg*8 + jj;   // < 512
                v[jj] = (f16)((lr < OO) ? wo[(size_t)k*OO + lr] * s : 0.0f);
            }
            bwo[k2] = v;
        }
    }

    // ---- swizzled A-read offsets ----
    const int ide = lg*16 + (lr ^ lg);        // even tiles
    const int ido = lg*16 + (lr ^ (4 + lg));  // odd tiles

    // ---- publish bases for h (row = 4lg+rr, col = 64g+16nt+lr) ----
    int wbase[NT], wxor[NT];
#pragma unroll
    for (int nt = 0; nt < NT; ++nt) {
        const int col = 64*g + 16*nt + lr;
        const int ktw = col >> 5, lgw = (col >> 3) & 3, j = col & 7;
        const int s = 4*(ktw & 1) + lgw;
        wbase[nt] = ktw*512 + lgw*128 + ((4*lg) ^ (s & 4))*8 + j;
        wxor[nt]  = (s & 3)*8;
    }
    // x publish: thread owns rows (xrow, xrow+8) at col xii; rows >= MB stay 0
    const int xrow = tid >> 6, xii = tid & 63;
    const bool ldx = (xrow < MB);
    const int xkt = 16 + (xii >> 5), xlg = (xii >> 3) & 3;
    const int xsw = 4*(xkt & 1) + xlg;
    const int xbi  = xkt*512 + xlg*128 + ((xrow    ) ^ xsw)*8 + (xii & 7);
    const int xbi2 = xkt*512 + xlg*128 + ((xrow + 8) ^ xsw)*8 + (xii & 7);

    // ---- state: hs[nt][rr] = h[row 4lg+rr][col 64g+16nt+lr] (C/D layout) ----
    f32x4 hs[NT];
#pragma unroll
    for (int nt = 0; nt < NT; ++nt) {
        const float v = h0[64*g + 16*nt + lr];
        hs[nt] = f32x4{v, v, v, v};
    }

    // ---- noise: real rows 0,1 live on lg==0 lanes; depth-2 register ring ----
    const bool ldn = (lg == 0);
    const float* np[MB];
#pragma unroll
    for (int rr = 0; rr < MB; ++rr)
        np[rr] = noise + (size_t)(b0 + rr)*TT*HH + 64*g + lr;
    float nzA[NT][MB] = {}, nzB[NT][MB] = {};
    if (ldn) {
#pragma unroll
        for (int nt = 0; nt < NT; ++nt)
#pragma unroll
            for (int rr = 0; rr < MB; ++rr) {
                nzA[nt][rr] = np[rr][16*nt];
                nzB[nt][rr] = np[rr][HH + 16*nt];
            }
    }

    // ---- x staging, one step ahead ----
    const float* xp = input + (size_t)(b0 + xrow)*TT*II + xii;
    float xv = ldx ? xp[0] : 0.0f;                     // x_0

    // ---- stream base: frag (st, nt) at wsp[st*2048 + nt*64] ----
    const uint4* wsp = ws + (size_t)(4*g)*64 + l;

    // ---- publish r_0 + alpha*x_0 into buffer 0 (single writer per slot) ----
#pragma unroll
    for (int nt = 0; nt < NT; ++nt)
#pragma unroll
        for (int rr = 0; rr < 4; ++rr)
            rpack[0][wbase[nt] + ((rr*8) ^ wxor[nt])] =
                (f16)(ALPHA * fmaxf(hs[nt][rr], 0.0f));
    rpack[0][xbi]  = (f16)(ALPHA * xv);
    rpack[0][xbi2] = (f16)0.0f;
    if (ldx) xv = xp[II];                              // x_1

    float* outb = out + (size_t)b0 * TT * OO;

    __syncthreads();

    int cur = 0;
#pragma unroll 1
    for (int t = 0; t < TT; ++t) {
        const f16x8* rvb = (const f16x8*)rpack[cur];

        // streamed B-frags, window 2 (constant indices only)
        f16x8 sw[NSTR][NT];
#define LDST(st, nt) (PACKED ? __builtin_bit_cast(f16x8, wsp[(st)*2048 + (nt)*64]) \
    : ((11 + (st)) < 16 \
        ? pack8(*(const float4*)(wrec + (size_t)(64*g + 16*(nt) + lr)*HH + (11+(st))*32 + lg*8), \
                *(const float4*)(wrec + (size_t)(64*g + 16*(nt) + lr)*HH + (11+(st))*32 + lg*8 + 4)) \
        : bw[0][0]))   /* placeholder, overwritten below for wi tiles */
#define ISSUE(st) { _Pragma("unroll") for (int nt = 0; nt < NT; ++nt) sw[st][nt] = LDST(st, nt); \
    if (!PACKED && (11 + (st)) >= 16) { _Pragma("unroll") for (int nt = 0; nt < NT; ++nt) { \
        const int col = 64*g + 16*nt + lr; f16x8 v; _Pragma("unroll") for (int jj = 0; jj < 8; ++jj) { \
            const int e = (11+(st))*32 + lg*8 + jj - HH; v[jj] = (f16)(wi[(size_t)e*HH + col] * si[e]); } \
        sw[st][nt] = v; } } }
#define CONSUME(st) { const int kt_ = 11 + (st); \
    const f16x8 a_ = rvb[kt_*64 + ((kt_ & 1) ? ido : ide)]; \
    _Pragma("unroll") for (int nt = 0; nt < NT; ++nt) hs[nt] = mfma16(a_, sw[st][nt], hs[nt]); }

        ISSUE(0); ISSUE(1);

        // C pre-accumulate: (1-a)h + sigma*n_t ; prefetch n_{t+2}
        if (t & 1) {
#pragma unroll
            for (int nt = 0; nt < NT; ++nt)
#pragma unroll
                for (int rr = 0; rr < 4; ++rr) {
                    float nv = (rr < MB && lg == 0) ? nzB[nt][rr] : 0.0f;
                    hs[nt][rr] = (1.0f - ALPHA)*hs[nt][rr] + NSTD*nv;
                }
            if (ldn && t + 2 < TT) {
#pragma unroll
                for (int nt = 0; nt < NT; ++nt)
#pragma unroll
                    for (int rr = 0; rr < MB; ++rr)
                        nzB[nt][rr] = np[rr][(size_t)(t + 2)*HH + 16*nt];
            }
        } else {
#pragma unroll
            for (int nt = 0; nt < NT; ++nt)
#pragma unroll
                for (int rr = 0; rr < 4; ++rr) {
                    float nv = (rr < MB && lg == 0) ? nzA[nt][rr] : 0.0f;
                    hs[nt][rr] = (1.0f - ALPHA)*hs[nt][rr] + NSTD*nv;
                }
            if (ldn && t + 2 < TT) {
#pragma unroll
                for (int nt = 0; nt < NT; ++nt)
#pragma unroll
                    for (int rr = 0; rr < MB; ++rr)
                        nzA[nt][rr] = np[rr][(size_t)(t + 2)*HH + 16*nt];
            }
        }

        // out-MFMA: wave g contributes K-tiles 2g,2g+1 of out[t] = relu(h_t) @ wo'
        {
            const f16x8 aA = rvb[(2*g)*64 + ide];          // tile 2g even
            const f16x8 aB = rvb[(2*g + 1)*64 + ido];      // tile 2g+1 odd
            f32x4 oacc = mfma16(aA, bwo[0], f32x4{0.f, 0.f, 0.f, 0.f});
            oacc = mfma16(aB, bwo[1], oacc);
            opart[cur][g][l] = oacc;
        }

        // reg tiles 0..3
#pragma unroll
        for (int kt = 0; kt < 4; ++kt) {
            const f16x8 a = rvb[kt*64 + ((kt & 1) ? ido : ide)];
#pragma unroll
            for (int nt = 0; nt < NT; ++nt) hs[nt] = mfma16(a, bw[kt][nt], hs[nt]);
        }
        CONSUME(0); ISSUE(2);
        // reg tiles 4..7
#pragma unroll
        for (int kt = 4; kt < 8; ++kt) {
            const f16x8 a = rvb[kt*64 + ((kt & 1) ? ido : ide)];
#pragma unroll
            for (int nt = 0; nt < NT; ++nt) hs[nt] = mfma16(a, bw[kt][nt], hs[nt]);
        }
        CONSUME(1); ISSUE(3);
        // LDS tiles 8..10
#pragma unroll
        for (int ktL = 0; ktL < NLDS; ++ktL) {
            const int kt = NAGR + ktL;
            const f16x8 a = rvb[kt*64 + ((kt & 1) ? ido : ide)];
#pragma unroll
            for (int nt = 0; nt < NT; ++nt)
                hs[nt] = mfma16(a, wrecL[ktL][4*g + nt][l], hs[nt]);
        }
        CONSUME(2); ISSUE(4);
        CONSUME(3); ISSUE(5);
        CONSUME(4); ISSUE(6);
        CONSUME(5);
        CONSUME(6);
#undef LDST
#undef ISSUE
#undef CONSUME

        // publish r_{t+1} (+ alpha*x_{t+1}; fake rows publish 0)
        const int nxt = cur ^ 1;
#pragma unroll
        for (int nt = 0; nt < NT; ++nt)
#pragma unroll
            for (int rr = 0; rr < 4; ++rr)
                rpack[nxt][wbase[nt] + ((rr*8) ^ wxor[nt])] =
                    (f16)(ALPHA * fmaxf(hs[nt][rr], 0.0f));
        rpack[nxt][xbi]  = (f16)(ALPHA * xv);
        rpack[nxt][xbi2] = (f16)0.0f;
        if (ldx && t + 2 < TT) xv = xp[(size_t)(t + 2)*II];

        __syncthreads();   // rpack[nxt] + opart[cur] visible

        if (g == NW - 1 && t > 0) {
            f32x4 s = opart[cur][0][l];
#pragma unroll
            for (int w = 1; w < NW; ++w) s += opart[cur][w][l];
            if (lg == 0 && lr < OO) {
#pragma unroll
                for (int rr = 0; rr < MB; ++rr)
                    outb[((size_t)rr*TT + (t - 1))*OO + lr] = s[rr];
            }
        }
        cur = nxt;
    }

    // drain: out[T-1] from rpack[cur] = alpha*relu(h_T)
    {
        const f16x8* rvb = (const f16x8*)rpack[cur];
        const f16x8 aA = rvb[(2*g)*64 + ide];
        const f16x8 aB = rvb[(2*g + 1)*64 + ido];
        f32x4 oacc = mfma16(aA, bwo[0], f32x4{0.f, 0.f, 0.f, 0.f});
        oacc = mfma16(aB, bwo[1], oacc);
        opart[cur][g][l] = oacc;
    }
    __syncthreads();
    if (g == NW - 1) {
        f32x4 s = opart[cur][0][l];
#pragma unroll
        for (int w = 1; w < NW; ++w) s += opart[cur][w][l];
        if (lg == 0 && lr < OO) {
#pragma unroll
            for (int rr = 0; rr < MB; ++rr)
                outb[((size_t)rr*TT + (TT - 1))*OO + lr] = s[rr];
        }
    }
}

extern "C" void kernel_launch(void* const* d_in, const int* in_sizes, int n_in,
                              void* d_out, int out_size, void* d_ws, size_t ws_size,
                              hipStream_t stream) {
    const float* input = (const float*)d_in[0];
    const float* noise = (const float*)d_in[1];
    const float* wi    = (const float*)d_in[2];
    const float* si    = (const float*)d_in[3];
    const float* wrec  = (const float*)d_in[4];
    const float* wo    = (const float*)d_in[5];
    const float* so    = (const float*)d_in[6];
    const float* h0    = (const float*)d_in[7];
    float* out = (float*)d_out;
    (void)in_sizes; (void)n_in; (void)out_size;

    if (ws_size >= (size_t)WS_NEED) {
        uint4* ws = (uint4*)d_ws;
        pack_kernel<<<dim3(WS_FRAGS / 512), dim3(512), 0, stream>>>(wrec, wi, si, ws);
        rnn_kernel<true><<<dim3(NBLK), dim3(512), 0, stream>>>(
            input, noise, wi, si, wrec, wo, so, h0, ws, out);
    } else {
        rnn_kernel<false><<<dim3(NBLK), dim3(512), 0, stream>>>(
            input, noise, wi, si, wrec, wo, so, h0, nullptr, out);
    }
}